// Round 11
// baseline (709.139 us; speedup 1.0000x reference)
//
#include <hip/hip_runtime.h>

#define NCOLS 16
#define NPAIR 120
#define NTRIP 560
#define OUTC  696
#define NREP  5     // diagnostic: repeat identical work so the dispatch > fill -> top-5 counters

__device__ __forceinline__ float tnorm(float a, float b, float lam) {
    float m = fmaxf(fmaxf(a, b), lam);          // -> v_max3_f32
    return a * b * __builtin_amdgcn_rcpf(m);
}

// Row-invariant index tables, hoisted to registers once per thread.
// pair[s*64+lane] = i | j<<8 ; trip[s*64+lane] = pid | k<<8
struct Tabs { unsigned pair[128]; unsigned trip[576]; };
constexpr Tabs make_tabs() {
    Tabs t{};
    int p = 0;
    for (int i = 0; i < NCOLS; ++i)
        for (int j = i + 1; j < NCOLS; ++j)
            t.pair[p++] = (unsigned)i | ((unsigned)j << 8);
    while (p < 128) t.pair[p++] = 0;
    int q = 0;
    for (int i = 0; i < NCOLS; ++i)
        for (int j = i + 1; j < NCOLS; ++j)
            for (int k = j + 1; k < NCOLS; ++k) {
                int pid = i * (31 - i) / 2 + (j - i - 1);   // lex pair rank
                t.trip[q++] = (unsigned)pid | ((unsigned)k << 8);
            }
    while (q < 576) t.trip[q++] = 0;
    return t;
}
__device__ const Tabs d_tabs = make_tabs();

// "paircache": wave-private LDS x[16]+pair[120] (no barriers; same-wave DS ops
// are in-order -- validated by R10 passing). Pairs computed once, reused by
// triples. Tiny LDS (2.2 KB/block) -> full 32 waves/CU occupancy. All global
// stores lane-striped (dense 256B per instr).
__global__ __launch_bounds__(256) void dubois_kernel(
    const float* __restrict__ x, const float* __restrict__ lam_p,
    float* __restrict__ out, int B, int iters, int nwaves, int nrep)
{
    __shared__ float sx[4][NCOLS];
    __shared__ float sp[4][NPAIR];

    const int lane = threadIdx.x & 63;
    const int w    = threadIdx.x >> 6;
    const int gwave = (blockIdx.x * blockDim.x + threadIdx.x) >> 6;
    const float lam = lam_p[0];

    const unsigned tp0 = d_tabs.pair[lane];
    const unsigned tp1 = d_tabs.pair[lane + 64];
    unsigned tt[9];
    #pragma unroll
    for (int s = 0; s < 9; ++s) tt[s] = d_tabs.trip[lane + s * 64];

    for (int rep = 0; rep < nrep; ++rep) {       // identical work each rep (idempotent)
        for (int it = 0; it < iters; ++it) {
            const int row = gwave + it * nwaves;
            if (row < B) {
                const float v = x[(size_t)row * NCOLS + (lane & 15)];
                float* __restrict__ orow = out + (size_t)row * OUTC;

                if (lane < NCOLS) { sx[w][lane] = v; orow[lane] = v; }

                // pairs: 2 steps, cached in sp for the triples
                {
                    const unsigned e = tp0;
                    const float pv = tnorm(sx[w][e & 255u], sx[w][(e >> 8) & 255u], lam);
                    sp[w][lane] = pv;
                    orow[NCOLS + lane] = pv;
                }
                if (lane < NPAIR - 64) {
                    const unsigned e = tp1;
                    const float pv = tnorm(sx[w][e & 255u], sx[w][(e >> 8) & 255u], lam);
                    sp[w][64 + lane] = pv;
                    orow[NCOLS + 64 + lane] = pv;
                }

                // triples: 9 steps, T(pair[pid], x[k])
                #pragma unroll
                for (int s = 0; s < 9; ++s) {
                    if (s < 8 || lane < 48) {    // 560 = 8*64 + 48
                        const unsigned e = tt[s];
                        const float a = sp[w][e & 255u];
                        const float c = sx[w][(e >> 8) & 255u];
                        orow[NCOLS + NPAIR + s * 64 + lane] = tnorm(a, c, lam);
                    }
                }
            }
        }
        asm volatile("" ::: "memory");           // forbid cross-rep store elision
    }
}

extern "C" void kernel_launch(void* const* d_in, const int* in_sizes, int n_in,
                              void* d_out, int out_size, void* d_ws, size_t ws_size,
                              hipStream_t stream) {
    const float* x   = (const float*)d_in[0];
    const float* lam = (const float*)d_in[1];
    float* out = (float*)d_out;

    const int B = in_sizes[0] / NCOLS;               // 131072
    const int threads = 256;
    const int blocks  = 2048;
    const int nwaves  = blocks * (threads / 64);     // 8192
    const int iters   = (B + nwaves - 1) / nwaves;   // 16

    dubois_kernel<<<blocks, threads, 0, stream>>>(x, lam, out, B, iters, nwaves, NREP);
}